// Round 6
// baseline (364.470 us; speedup 1.0000x reference)
//
#include <hip/hip_runtime.h>
#include <stdint.h>

#define DIM 512

typedef short short8 __attribute__((ext_vector_type(8)));
typedef float floatx4 __attribute__((ext_vector_type(4)));

// f32 -> bf16 round-to-nearest-even
__device__ __forceinline__ unsigned short f2b(float x){
  uint32_t u = __float_as_uint(x);
  u += 0x7FFFu + ((u >> 16) & 1u);
  return (unsigned short)(u >> 16);
}
__device__ __forceinline__ float blo(uint32_t u){ return __uint_as_float(u << 16); }
__device__ __forceinline__ float bhi(uint32_t u){ return __uint_as_float(u & 0xFFFF0000u); }

// async global->LDS, 16 B per lane. LDS dest = wave-uniform base + lane*16.
__device__ __forceinline__ void gld_lds16(const void* g, void* l){
  __builtin_amdgcn_global_load_lds(
      (const __attribute__((address_space(1))) void*)g,
      (__attribute__((address_space(3))) void*)l, 16, 0, 0);
}

// ---------------- fused prep: edge-count + x->bf16 cvt + weight pack ----------------
__global__ __launch_bounds__(256)
void k_prep(const int* __restrict__ ei, int* __restrict__ cnt, int E, int nCnt,
            const float* __restrict__ W1, unsigned short* __restrict__ W1p,
            const float* __restrict__ W2, unsigned short* __restrict__ W2p,
            const float* __restrict__ x, unsigned short* __restrict__ xb, long n8)
{
  const int b = blockIdx.x;
  const int t = threadIdx.x;
  if (b < nCnt){
    int e = b * 256 + t;
    if (e < E) atomicAdd(&cnt[ei[E + e]], 1);
  } else if (b < nCnt + 2048){
    int pb = b - nCnt;                       // 0..2047
    int g = (pb & 1023) * 256 + t;           // 0..DIM*DIM-1
    const float* W = (pb < 1024) ? W1 : W2;
    unsigned short* Wp = (pb < 1024) ? W1p : W2p;
    int k = g >> 9, n = g & 511;
    int idx = ((n >> 4) << 13) + ((k >> 3) << 7) + ((n & 15) << 3) + (k & 7);
    Wp[idx] = f2b(W[g]);
  } else {
    long i = (long)(b - nCnt - 2048) * 256 + t;
    if (i < n8){
      float4 v0 = ((const float4*)x)[i * 2];
      float4 v1 = ((const float4*)x)[i * 2 + 1];
      uint4 o;
      o.x = (uint32_t)f2b(v0.x) | ((uint32_t)f2b(v0.y) << 16);
      o.y = (uint32_t)f2b(v0.z) | ((uint32_t)f2b(v0.w) << 16);
      o.z = (uint32_t)f2b(v1.x) | ((uint32_t)f2b(v1.y) << 16);
      o.w = (uint32_t)f2b(v1.z) | ((uint32_t)f2b(v1.w) << 16);
      ((uint4*)xb)[i] = o;
    }
  }
}

// ---------------- CSR build ----------------
__global__ __launch_bounds__(256)
void k_bsum(const int* __restrict__ cnt, int* __restrict__ partial, int n){
  __shared__ int sh[4];
  int t = threadIdx.x;
  int base = blockIdx.x * 1024 + t * 4;
  int s = 0;
  if (base + 3 < n){
    int4 v = *(const int4*)(cnt + base);
    s = v.x + v.y + v.z + v.w;
  } else {
    for (int j = 0; j < 4; ++j) if (base + j < n) s += cnt[base + j];
  }
  for (int d = 32; d; d >>= 1) s += __shfl_down(s, d);
  if ((t & 63) == 0) sh[t >> 6] = s;
  __syncthreads();
  if (t == 0) partial[blockIdx.x] = sh[0] + sh[1] + sh[2] + sh[3];
}

// fscan: block scan of cnt -> rowptr (exclusive) + dis = rsqrt(deg+1), pscan folded in
__global__ __launch_bounds__(256)
void k_fscan(const int* __restrict__ cnt, const int* __restrict__ partial,
             int* __restrict__ rowptr, float* __restrict__ dis, int n, int nb){
  __shared__ int sh[256];
  __shared__ int pref_sh;
  int t = threadIdx.x;
  if (t < 64){
    int v = (t < nb) ? partial[t] : 0;
    int incl = v;
    #pragma unroll
    for (int d = 1; d < 64; d <<= 1){
      int u = __shfl_up(incl, d);
      if (t >= d) incl += u;
    }
    int bm1 = (int)blockIdx.x - 1;
    int pref = __shfl(incl, bm1 < 0 ? 0 : bm1);
    if (t == 0) pref_sh = (blockIdx.x == 0) ? 0 : pref;
    int total = __shfl(incl, nb - 1);
    if (t == 0 && blockIdx.x == 0) rowptr[n] = total;
  }
  int base = blockIdx.x * 1024 + t * 4;
  int v0=0, v1=0, v2=0, v3=0;
  if (base + 3 < n){
    int4 v = *(const int4*)(cnt + base);
    v0=v.x; v1=v.y; v2=v.z; v3=v.w;
  } else {
    if (base   < n) v0 = cnt[base];
    if (base+1 < n) v1 = cnt[base+1];
    if (base+2 < n) v2 = cnt[base+2];
    if (base+3 < n) v3 = cnt[base+3];
  }
  int tsum = v0 + v1 + v2 + v3;
  sh[t] = tsum;
  __syncthreads();
  for (int off = 1; off < 256; off <<= 1){
    int u = (t >= off) ? sh[t - off] : 0;
    __syncthreads();
    sh[t] += u;
    __syncthreads();
  }
  int excl = sh[t] - tsum + pref_sh;
  if (base   < n){ rowptr[base  ] = excl;             dis[base  ] = rsqrtf((float)v0 + 1.0f); }
  if (base+1 < n){ rowptr[base+1] = excl + v0;        dis[base+1] = rsqrtf((float)v1 + 1.0f); }
  if (base+2 < n){ rowptr[base+2] = excl + v0 + v1;   dis[base+2] = rsqrtf((float)v2 + 1.0f); }
  if (base+3 < n){ rowptr[base+3] = excl + v0+v1+v2;  dis[base+3] = rsqrtf((float)v3 + 1.0f); }
}

__global__ void k_fill(const int* __restrict__ ei, const int* __restrict__ rowptr,
                       int* __restrict__ fill, int* __restrict__ colidx, int E){
  int e = blockIdx.x * blockDim.x + threadIdx.x;
  if (e < E){
    int d = ei[E + e];
    int pos = rowptr[d] + atomicAdd(&fill[d], 1);
    colidx[pos] = ei[e];
  }
}

// ---------------- GEMM: C = dis-scaled (A @ W), bf16 in/out, LDS-staged ----------------
// ROUND-4 KNOWN-GOOD STRUCTURE (round-5 counted-vmcnt pipeline raced: compiler
// may reorder global_load_lds issues -> vmcnt(4) retires the wrong ops ->
// intermittent stale-B reads. Do not re-introduce without issue-order pinning.)
// 128x128 tile, BK=64, 8 K-steps, 4 waves, 32KB LDS single-buffered,
// __syncthreads drain each step. XCD-bijective swizzle (m204); (256,4) for
// 4 blocks/CU. A-swizzle on GLOBAL addr at staging; D map row=q*4+r, col=l15.
__global__ __launch_bounds__(256, 4)
void k_gemm(const unsigned short* __restrict__ A, const unsigned short* __restrict__ Wp,
            const float* __restrict__ dis, unsigned short* __restrict__ C, int Nr)
{
  __shared__ unsigned short smem[16384];   // A: [0,8192) elems, B: [8192,16384)
  const int tid  = threadIdx.x;
  const int w    = tid >> 6;
  const int lane = tid & 63;
  const int l15  = lane & 15;
  const int q    = lane >> 4;

  // XCD-bijective remap of the linear block id
  const int nwg  = gridDim.x * gridDim.y;
  const int orig = blockIdx.y * gridDim.x + blockIdx.x;
  const int xcd  = orig & 7;
  const int qq   = nwg >> 3, rr = nwg & 7;
  const int wgid = (xcd < rr ? xcd * (qq + 1) : rr * (qq + 1) + (xcd - rr) * qq) + (orig >> 3);

  const int R0   = (wgid >> 2) * 128;      // m-tile
  const int n0   = (wgid & 3) * 128;       // n-tile (fastest -> A panel reuse)
  const int h    = w & 1;
  const int v    = w >> 1;

  const int srow   = lane >> 3;                      // row within an 8-row issue
  const int schunk = (lane & 7) ^ (srow & 7);        // swizzled global chunk
  const int X = l15 & 7;

  int garow[4];
  #pragma unroll
  for (int j = 0; j < 4; ++j){
    int gr = R0 + (w * 4 + j) * 8 + srow;
    if (gr >= Nr) gr = Nr - 1;
    garow[j] = gr;
  }
  const size_t wpbase = (size_t)(n0 >> 4) * 8192;    // elem offset of first n-group

  floatx4 acc[4][4];
  #pragma unroll
  for (int s = 0; s < 4; ++s)
    #pragma unroll
    for (int nt = 0; nt < 4; ++nt)
      acc[s][nt] = (floatx4){0,0,0,0};

  for (int t = 0; t < 8; ++t){
    if (t) __syncthreads();
    #pragma unroll
    for (int j = 0; j < 4; ++j){
      const int ia = w * 4 + j;                      // 0..15
      gld_lds16(A + (size_t)garow[j] * DIM + t * 64 + schunk * 8, &smem[ia * 512]);
      gld_lds16(Wp + wpbase + (size_t)(ia >> 1) * 8192 + t * 1024 + (ia & 1) * 512 + lane * 8,
                &smem[8192 + ia * 512]);
    }
    __syncthreads();   // drains vmcnt(0) before barrier -> LDS valid

    #pragma unroll
    for (int ksl = 0; ksl < 2; ++ksl){
      short8 a[4], b[4];
      #pragma unroll
      for (int s = 0; s < 4; ++s){
        const int rho = h * 64 + s * 16 + l15;
        const int cc  = (ksl * 4 + q) ^ X;
        a[s] = *(const short8*)&smem[rho * 64 + cc * 8];
      }
      #pragma unroll
      for (int nt = 0; nt < 4; ++nt)
        b[nt] = *(const short8*)&smem[8192 + (v * 4 + nt) * 1024 + ksl * 512 + q * 128 + l15 * 8];
      #pragma unroll
      for (int nt = 0; nt < 4; ++nt){
        acc[0][nt] = __builtin_amdgcn_mfma_f32_16x16x32_bf16(a[0], b[nt], acc[0][nt], 0, 0, 0);
        acc[1][nt] = __builtin_amdgcn_mfma_f32_16x16x32_bf16(a[1], b[nt], acc[1][nt], 0, 0, 0);
        acc[2][nt] = __builtin_amdgcn_mfma_f32_16x16x32_bf16(a[2], b[nt], acc[2][nt], 0, 0, 0);
        acc[3][nt] = __builtin_amdgcn_mfma_f32_16x16x32_bf16(a[3], b[nt], acc[3][nt], 0, 0, 0);
      }
    }
  }

  #pragma unroll
  for (int s = 0; s < 4; ++s){
    #pragma unroll
    for (int r = 0; r < 4; ++r){
      const int row = R0 + h * 64 + s * 16 + q * 4 + r;
      if (row < Nr){
        const float ds = dis[row];
        size_t base = (size_t)row * DIM + n0 + v * 64 + l15;
        #pragma unroll
        for (int nt = 0; nt < 4; ++nt)
          C[base + nt * 16] = f2b(acc[s][nt][r] * ds);
      }
    }
  }
}

// ---------------- Aggregation: out_i = dis_i * (H[i] + sum_{s in N(i)} H[s]) + b ----
// TWO nodes per wave (32 lanes x 16 elems each, 2x uint4 per lane per row):
// doubles the independent load chains per wave; with the 2-deep edge unroll up
// to 8 row-loads in flight. [r5: correctness-verified in pre-timing check]
#define ACC8(U, K) \
  a##K##0 += blo(U.x); a##K##1 += bhi(U.x); a##K##2 += blo(U.y); a##K##3 += bhi(U.y); \
  a##K##4 += blo(U.z); a##K##5 += bhi(U.z); a##K##6 += blo(U.w); a##K##7 += bhi(U.w);

template<int RELU, int OUTBF16>
__global__ __launch_bounds__(256)
void k_agg(const unsigned short* __restrict__ H, const int* __restrict__ rowptr,
           const int* __restrict__ colidx, const float* __restrict__ dis,
           const float* __restrict__ bias, void* __restrict__ outp, int Nn)
{
  const int l    = threadIdx.x & 63;
  const int half = l >> 5;                 // node slot within wave
  const int c    = l & 31;                 // lane within node
  const int i    = blockIdx.x * 8 + ((threadIdx.x >> 6) << 1) + half;
  if (i >= Nn) return;
  const int f = c * 16;                    // 16 elems per lane
  const float di = dis[i];

  float a00,a01,a02,a03,a04,a05,a06,a07, a10,a11,a12,a13,a14,a15,a16,a17;
  {
    const uint4* hp = (const uint4*)(H + (size_t)i * DIM + f);
    uint4 u0 = hp[0], u1 = hp[1];
    a00 = blo(u0.x); a01 = bhi(u0.x); a02 = blo(u0.y); a03 = bhi(u0.y);
    a04 = blo(u0.z); a05 = bhi(u0.z); a06 = blo(u0.w); a07 = bhi(u0.w);
    a10 = blo(u1.x); a11 = bhi(u1.x); a12 = blo(u1.y); a13 = bhi(u1.y);
    a14 = blo(u1.z); a15 = bhi(u1.z); a16 = blo(u1.w); a17 = bhi(u1.w);
  }
  int e  = rowptr[i];
  const int r1 = rowptr[i + 1];
  for (; e + 1 < r1; e += 2){
    const uint4* p0 = (const uint4*)(H + (size_t)colidx[e]     * DIM + f);
    const uint4* p1 = (const uint4*)(H + (size_t)colidx[e + 1] * DIM + f);
    uint4 u0 = p0[0], u1 = p0[1];
    uint4 v0 = p1[0], v1 = p1[1];
    ACC8(u0, 0) ACC8(u1, 1)
    ACC8(v0, 0) ACC8(v1, 1)
  }
  if (e < r1){
    const uint4* p0 = (const uint4*)(H + (size_t)colidx[e] * DIM + f);
    uint4 u0 = p0[0], u1 = p0[1];
    ACC8(u0, 0) ACC8(u1, 1)
  }
  float4 b0 = *(const float4*)(bias + f);
  float4 b1 = *(const float4*)(bias + f + 4);
  float4 b2 = *(const float4*)(bias + f + 8);
  float4 b3 = *(const float4*)(bias + f + 12);
  a00 = a00 * di + b0.x; a01 = a01 * di + b0.y; a02 = a02 * di + b0.z; a03 = a03 * di + b0.w;
  a04 = a04 * di + b1.x; a05 = a05 * di + b1.y; a06 = a06 * di + b1.z; a07 = a07 * di + b1.w;
  a10 = a10 * di + b2.x; a11 = a11 * di + b2.y; a12 = a12 * di + b2.z; a13 = a13 * di + b2.w;
  a14 = a14 * di + b3.x; a15 = a15 * di + b3.y; a16 = a16 * di + b3.z; a17 = a17 * di + b3.w;
  if (RELU){
    a00 = fmaxf(a00, 0.f); a01 = fmaxf(a01, 0.f); a02 = fmaxf(a02, 0.f); a03 = fmaxf(a03, 0.f);
    a04 = fmaxf(a04, 0.f); a05 = fmaxf(a05, 0.f); a06 = fmaxf(a06, 0.f); a07 = fmaxf(a07, 0.f);
    a10 = fmaxf(a10, 0.f); a11 = fmaxf(a11, 0.f); a12 = fmaxf(a12, 0.f); a13 = fmaxf(a13, 0.f);
    a14 = fmaxf(a14, 0.f); a15 = fmaxf(a15, 0.f); a16 = fmaxf(a16, 0.f); a17 = fmaxf(a17, 0.f);
  }
  if (OUTBF16){
    uint4 o0, o1;
    o0.x = (uint32_t)f2b(a00) | ((uint32_t)f2b(a01) << 16);
    o0.y = (uint32_t)f2b(a02) | ((uint32_t)f2b(a03) << 16);
    o0.z = (uint32_t)f2b(a04) | ((uint32_t)f2b(a05) << 16);
    o0.w = (uint32_t)f2b(a06) | ((uint32_t)f2b(a07) << 16);
    o1.x = (uint32_t)f2b(a10) | ((uint32_t)f2b(a11) << 16);
    o1.y = (uint32_t)f2b(a12) | ((uint32_t)f2b(a13) << 16);
    o1.z = (uint32_t)f2b(a14) | ((uint32_t)f2b(a15) << 16);
    o1.w = (uint32_t)f2b(a16) | ((uint32_t)f2b(a17) << 16);
    uint4* op = (uint4*)outp + (size_t)i * 64 + c * 2;
    op[0] = o0;
    op[1] = o1;
  } else {
    float* op = (float*)outp + (size_t)i * DIM + f;
    float4 o0; o0.x = a00; o0.y = a01; o0.z = a02; o0.w = a03;
    float4 o1; o1.x = a04; o1.y = a05; o1.z = a06; o1.w = a07;
    float4 o2; o2.x = a10; o2.y = a11; o2.z = a12; o2.w = a13;
    float4 o3; o3.x = a14; o3.y = a15; o3.z = a16; o3.w = a17;
    *(float4*)op        = o0;
    *(float4*)(op + 4)  = o1;
    *(float4*)(op + 8)  = o2;
    *(float4*)(op + 12) = o3;
  }
}

// ---------------- launch ----------------
extern "C" void kernel_launch(void* const* d_in, const int* in_sizes, int n_in,
                              void* d_out, int out_size, void* d_ws, size_t ws_size,
                              hipStream_t stream)
{
  const float* x  = (const float*)d_in[0];
  const int*   ei = (const int*)d_in[1];
  const float* W1 = (const float*)d_in[2];
  const float* b1 = (const float*)d_in[3];
  const float* W2 = (const float*)d_in[4];
  const float* b2 = (const float*)d_in[5];
  const int N = in_sizes[0] / DIM;
  const int E = in_sizes[1] / 2;

  char* p = (char*)d_ws;
  auto alloc = [&](size_t bytes) -> char* {
    char* r = p; p += (bytes + 255) & ~(size_t)255; return r;
  };
  unsigned short* xb   = (unsigned short*)alloc((size_t)N * DIM * 2);  // bf16 A (layer 1 and 2)
  unsigned short* hb   = (unsigned short*)alloc((size_t)N * DIM * 2);  // GEMM output (bf16)
  unsigned short* W1p  = (unsigned short*)alloc((size_t)DIM * DIM * 2);
  unsigned short* W2p  = (unsigned short*)alloc((size_t)DIM * DIM * 2);
  float* dis    = (float*)alloc((size_t)N * 4);
  char*  cz     = alloc((size_t)N * 4);          // cnt
  char*  fz     = alloc((size_t)N * 4);          // fill (contiguous with cnt)
  int*   cnt    = (int*)cz;
  int*   fill   = (int*)fz;
  int*   rowptr = (int*)alloc((size_t)(N + 1) * 4);
  int*   colidx = (int*)alloc((size_t)E * 4);
  int*   partial= (int*)alloc(64 * 4);

  const int nsb = (N + 1023) / 1024;   // scan blocks (<=64)

  // zero cnt+fill in one async memset (contiguous in ws)
  hipMemsetAsync(cz, 0, (size_t)(fz - cz) + (size_t)N * 4, stream);

  // fused prep: count + pack(W1,W2) + cvt
  long n8 = (long)N * DIM / 8;
  const int nCnt = (E + 255) / 256;
  const int nCvt = (int)((n8 + 255) / 256);
  k_prep<<<nCnt + 2048 + nCvt, 256, 0, stream>>>(ei, cnt, E, nCnt, W1, W1p, W2, W2p, x, xb, n8);

  // CSR scan + fill
  k_bsum<<<nsb, 256, 0, stream>>>(cnt, partial, N);
  k_fscan<<<nsb, 256, 0, stream>>>(cnt, partial, rowptr, dis, N, nsb);
  k_fill<<<(E + 255) / 256, 256, 0, stream>>>(ei, rowptr, fill, colidx, E);

  // grid: wgid = m*4 + n decoded in-kernel after XCD-bijective remap
  dim3 gg(DIM / 128, (N + 127) / 128);
  // layer 1: H1 = dis * (x @ W1); x2 = relu(dis * agg(H1) + b1) in bf16 (into xb)
  k_gemm<<<gg, 256, 0, stream>>>(xb, W1p, dis, hb, N);
  k_agg<1, 1><<<(N + 7) / 8, 256, 0, stream>>>(hb, rowptr, colidx, dis, b1, xb, N);
  // layer 2: H2 = dis * (x2 @ W2); out f32
  k_gemm<<<gg, 256, 0, stream>>>(xb, W2p, dis, hb, N);
  k_agg<0, 0><<<(N + 7) / 8, 256, 0, stream>>>(hb, rowptr, colidx, dis, b2, d_out, N);
}